// Round 1
// baseline (244.546 us; speedup 1.0000x reference)
//
#include <hip/hip_runtime.h>
#include <math.h>

#define B_ 32
#define C_ 256
#define H_ 56
#define W_ 56
#define HW_ (H_*W_)        // 3136
#define R_ 16
#define K_ 7

__device__ __forceinline__ float sigmoidf_(float v) { return 1.0f / (1.0f + expf(-v)); }

// ---------------- Kernel 1: per-(b,c) mean + max over HW ----------------
__global__ void k_pool_bc(const float* __restrict__ x,
                          float* __restrict__ avg, float* __restrict__ mx) {
    const int bc = blockIdx.x;                      // 0 .. B*C-1
    const float4* xp = (const float4*)(x + (size_t)bc * HW_);
    float s = 0.0f, m = -INFINITY;
    for (int i = threadIdx.x; i < HW_ / 4; i += blockDim.x) {
        float4 v = xp[i];
        s += v.x + v.y + v.z + v.w;
        m = fmaxf(m, fmaxf(fmaxf(v.x, v.y), fmaxf(v.z, v.w)));
    }
    // wave (64-lane) reduce
    #pragma unroll
    for (int off = 32; off > 0; off >>= 1) {
        s += __shfl_down(s, off, 64);
        m  = fmaxf(m, __shfl_down(m, off, 64));
    }
    __shared__ float ss[4], sm[4];
    const int wave = threadIdx.x >> 6;
    if ((threadIdx.x & 63) == 0) { ss[wave] = s; sm[wave] = m; }
    __syncthreads();
    if (threadIdx.x == 0) {
        float S = ss[0] + ss[1] + ss[2] + ss[3];
        float M = fmaxf(fmaxf(sm[0], sm[1]), fmaxf(sm[2], sm[3]));
        avg[bc] = S * (1.0f / HW_);
        mx[bc]  = M;
    }
}

// ---------------- Kernel 2: shared MLP -> channel attention ----------------
// ca[b,c] = sigmoid( sum_r w2[c,r] * ( relu(sum_c' w1[r,c']*avg[b,c'])
//                                    + relu(sum_c' w1[r,c']*mx[b,c']) ) )
__global__ void k_mlp_ca(const float* __restrict__ avg, const float* __restrict__ mx,
                         const float* __restrict__ w1, const float* __restrict__ w2,
                         float* __restrict__ ca) {
    const int b = blockIdx.x;
    __shared__ float sa_[C_], sm_[C_], h_[R_];
    const int t = threadIdx.x;                      // blockDim.x == C_
    sa_[t] = avg[b * C_ + t];
    sm_[t] = mx[b * C_ + t];
    __syncthreads();
    if (t < R_) {
        float ha = 0.0f, hm = 0.0f;
        for (int c = 0; c < C_; ++c) {
            const float wv = w1[t * C_ + c];
            ha += wv * sa_[c];
            hm += wv * sm_[c];
        }
        h_[t] = fmaxf(ha, 0.0f) + fmaxf(hm, 0.0f);
    }
    __syncthreads();
    float acc = 0.0f;
    #pragma unroll
    for (int r = 0; r < R_; ++r) acc += w2[t * R_ + r] * h_[r];
    ca[b * C_ + t] = sigmoidf_(acc);
}

// ---------------- Kernel 3: spatial pooled = {mean_c, max_c} of x*ca ----------------
__global__ void k_spatial_pool(const float* __restrict__ x, const float* __restrict__ ca,
                               float* __restrict__ pooled) {
    const int idx = blockIdx.x * blockDim.x + threadIdx.x;   // over B*HW/4
    if (idx >= B_ * (HW_ / 4)) return;
    const int b = idx / (HW_ / 4);
    const int q = idx % (HW_ / 4);
    const float4* xp = (const float4*)(x + (size_t)b * C_ * HW_);
    const float* cab = ca + b * C_;
    float4 s = {0.f, 0.f, 0.f, 0.f};
    float4 m = {-INFINITY, -INFINITY, -INFINITY, -INFINITY};
    for (int c = 0; c < C_; ++c) {
        const float a = cab[c];
        float4 v = xp[c * (HW_ / 4) + q];
        v.x *= a; v.y *= a; v.z *= a; v.w *= a;
        s.x += v.x; s.y += v.y; s.z += v.z; s.w += v.w;
        m.x = fmaxf(m.x, v.x); m.y = fmaxf(m.y, v.y);
        m.z = fmaxf(m.z, v.z); m.w = fmaxf(m.w, v.w);
    }
    const float inv = 1.0f / C_;
    float4 sm4 = {s.x * inv, s.y * inv, s.z * inv, s.w * inv};
    ((float4*)(pooled + (size_t)b * 2 * HW_))[q]      = sm4;
    ((float4*)(pooled + (size_t)b * 2 * HW_ + HW_))[q] = m;
}

// ---------------- Kernel 4: 7x7 conv (pad 3) over pooled -> sigmoid -> sa ----------------
__global__ void k_conv_sa(const float* __restrict__ pooled, const float* __restrict__ wsp,
                          float* __restrict__ sa) {
    __shared__ float wv[2 * K_ * K_];
    if (threadIdx.x < 2 * K_ * K_) wv[threadIdx.x] = wsp[threadIdx.x];
    __syncthreads();
    const int idx = blockIdx.x * blockDim.x + threadIdx.x;   // over B*HW
    if (idx >= B_ * HW_) return;
    const int b = idx / HW_;
    const int hw = idx % HW_;
    const int h = hw / W_, w = hw % W_;
    const float* pa = pooled + (size_t)b * 2 * HW_;
    const float* pm = pa + HW_;
    float acc = 0.0f;
    #pragma unroll
    for (int ky = 0; ky < K_; ++ky) {
        const int y = h + ky - 3;
        if (y < 0 || y >= H_) continue;
        #pragma unroll
        for (int kx = 0; kx < K_; ++kx) {
            const int xx = w + kx - 3;
            if (xx < 0 || xx >= W_) continue;
            const int o = y * W_ + xx;
            acc += wv[ky * K_ + kx] * pa[o] + wv[K_ * K_ + ky * K_ + kx] * pm[o];
        }
    }
    sa[idx] = sigmoidf_(acc);
}

// ---------------- Kernel 5: out = x * (1 + ca*sa) ----------------
__global__ void k_finalize(const float* __restrict__ x, const float* __restrict__ ca,
                           const float* __restrict__ sa, float* __restrict__ out) {
    const size_t idx = (size_t)blockIdx.x * blockDim.x + threadIdx.x;  // over B*C*HW/4
    if (idx >= (size_t)B_ * C_ * (HW_ / 4)) return;
    const size_t e = idx * 4;
    const int b  = (int)(e / ((size_t)C_ * HW_));
    const int c  = (int)((e / HW_) % C_);
    const int hw = (int)(e % HW_);
    const float a = ca[b * C_ + c];
    const float4 s4 = *(const float4*)(sa + (size_t)b * HW_ + hw);
    const float4 v  = *(const float4*)(x + e);
    float4 o;
    o.x = v.x * (1.0f + a * s4.x);
    o.y = v.y * (1.0f + a * s4.y);
    o.z = v.z * (1.0f + a * s4.z);
    o.w = v.w * (1.0f + a * s4.w);
    *(float4*)((float*)out + e) = o;
}

extern "C" void kernel_launch(void* const* d_in, const int* in_sizes, int n_in,
                              void* d_out, int out_size, void* d_ws, size_t ws_size,
                              hipStream_t stream) {
    const float* x   = (const float*)d_in[0];
    const float* w1  = (const float*)d_in[1];
    const float* w2  = (const float*)d_in[2];
    const float* wsp = (const float*)d_in[3];
    float* out = (float*)d_out;

    // workspace layout (floats)
    float* ws    = (float*)d_ws;
    float* avg    = ws;                         // B*C
    float* mx     = avg + B_ * C_;              // B*C
    float* ca     = mx + B_ * C_;               // B*C
    float* pooled = ca + B_ * C_;               // B*2*HW
    float* sa     = pooled + (size_t)B_ * 2 * HW_;  // B*HW

    // 1) channel-wise pooling
    k_pool_bc<<<B_ * C_, 256, 0, stream>>>(x, avg, mx);
    // 2) MLP -> channel attention
    k_mlp_ca<<<B_, C_, 0, stream>>>(avg, mx, w1, w2, ca);
    // 3) spatial pooling of x*ca
    {
        const int n = B_ * (HW_ / 4);
        k_spatial_pool<<<(n + 255) / 256, 256, 0, stream>>>(x, ca, pooled);
    }
    // 4) 7x7 conv + sigmoid
    {
        const int n = B_ * HW_;
        k_conv_sa<<<(n + 255) / 256, 256, 0, stream>>>(pooled, wsp, sa);
    }
    // 5) residual finalize
    {
        const size_t n = (size_t)B_ * C_ * (HW_ / 4);
        k_finalize<<<(int)((n + 255) / 256), 256, 0, stream>>>(x, ca, sa, out);
    }
}

// Round 2
// 233.260 us; speedup vs baseline: 1.0484x; 1.0484x over previous
//
#include <hip/hip_runtime.h>
#include <math.h>

#define B_ 32
#define C_ 256
#define H_ 56
#define W_ 56
#define HW_ (H_*W_)        // 3136
#define Q_ (HW_/4)         // 784 float4 positions per (b,c) map
#define R_ 16
#define K_ 7

__device__ __forceinline__ float sigmoidf_(float v) { return 1.0f / (1.0f + expf(-v)); }

// ---------------- Kernel 1: per-(b,c) mean + max over HW ----------------
__global__ void k_pool_bc(const float* __restrict__ x,
                          float* __restrict__ avg, float* __restrict__ mx) {
    const int bc = blockIdx.x;                      // 0 .. B*C-1
    const float4* xp = (const float4*)(x + (size_t)bc * HW_);
    float s = 0.0f, m = -INFINITY;
    for (int i = threadIdx.x; i < Q_; i += blockDim.x) {
        float4 v = xp[i];
        s += v.x + v.y + v.z + v.w;
        m = fmaxf(m, fmaxf(fmaxf(v.x, v.y), fmaxf(v.z, v.w)));
    }
    // wave (64-lane) reduce
    #pragma unroll
    for (int off = 32; off > 0; off >>= 1) {
        s += __shfl_down(s, off, 64);
        m  = fmaxf(m, __shfl_down(m, off, 64));
    }
    __shared__ float ss[4], sm[4];
    const int wave = threadIdx.x >> 6;
    if ((threadIdx.x & 63) == 0) { ss[wave] = s; sm[wave] = m; }
    __syncthreads();
    if (threadIdx.x == 0) {
        float S = ss[0] + ss[1] + ss[2] + ss[3];
        float M = fmaxf(fmaxf(sm[0], sm[1]), fmaxf(sm[2], sm[3]));
        avg[bc] = S * (1.0f / HW_);
        mx[bc]  = M;
    }
}

// ---------------- Kernel 2: shared MLP -> channel attention ----------------
__global__ void k_mlp_ca(const float* __restrict__ avg, const float* __restrict__ mx,
                         const float* __restrict__ w1, const float* __restrict__ w2,
                         float* __restrict__ ca) {
    const int b = blockIdx.x;
    __shared__ float sa_[C_], sm_[C_], h_[R_];
    const int t = threadIdx.x;                      // blockDim.x == C_
    sa_[t] = avg[b * C_ + t];
    sm_[t] = mx[b * C_ + t];
    __syncthreads();
    if (t < R_) {
        float ha = 0.0f, hm = 0.0f;
        for (int c = 0; c < C_; ++c) {
            const float wv = w1[t * C_ + c];
            ha += wv * sa_[c];
            hm += wv * sm_[c];
        }
        h_[t] = fmaxf(ha, 0.0f) + fmaxf(hm, 0.0f);
    }
    __syncthreads();
    float acc = 0.0f;
    #pragma unroll
    for (int r = 0; r < R_; ++r) acc += w2[t * R_ + r] * h_[r];
    ca[b * C_ + t] = sigmoidf_(acc);
}

// ---------------- Kernel 3 (v2): spatial pooled = {mean_c, max_c} of x*ca ----------------
// Block: 256 threads = 16 q-positions (float4) x 16 channel-groups (16 ch each).
// Grid: (Q_/16, B) = (49, 32) = 1568 blocks.
__global__ void __launch_bounds__(256)
k_spatial_pool(const float* __restrict__ x, const float* __restrict__ ca,
               float* __restrict__ pooled) {
    const int b  = blockIdx.y;
    const int q0 = blockIdx.x * 16;
    const int t  = threadIdx.x;
    const int tq = t & 15;          // q offset within block
    const int tc = t >> 4;          // channel group 0..15
    const int q  = q0 + tq;

    const float4* xp = (const float4*)(x + (size_t)b * C_ * HW_);
    const float* cab = ca + b * C_;

    float4 s = {0.f, 0.f, 0.f, 0.f};
    float4 m = {-INFINITY, -INFINITY, -INFINITY, -INFINITY};
    #pragma unroll 4
    for (int i = 0; i < 16; ++i) {
        const int c = tc * 16 + i;
        const float a = cab[c];
        float4 v = xp[(size_t)c * Q_ + q];
        v.x *= a; v.y *= a; v.z *= a; v.w *= a;
        s.x += v.x; s.y += v.y; s.z += v.z; s.w += v.w;
        m.x = fmaxf(m.x, v.x); m.y = fmaxf(m.y, v.y);
        m.z = fmaxf(m.z, v.z); m.w = fmaxf(m.w, v.w);
    }

    __shared__ float4 ls[256];
    __shared__ float4 lm[256];
    ls[t] = s; lm[t] = m;
    __syncthreads();
    // reduce across the 16 channel-groups (stride 16 in t-index space)
    #pragma unroll
    for (int st = 8; st >= 1; st >>= 1) {
        if (tc < st) {
            const int o = t + st * 16;
            float4 os = ls[o], om = lm[o];
            s.x += os.x; s.y += os.y; s.z += os.z; s.w += os.w;
            m.x = fmaxf(m.x, om.x); m.y = fmaxf(m.y, om.y);
            m.z = fmaxf(m.z, om.z); m.w = fmaxf(m.w, om.w);
            ls[t] = s; lm[t] = m;
        }
        __syncthreads();
    }
    if (tc == 0) {
        const float inv = 1.0f / C_;
        float4 sm4 = {s.x * inv, s.y * inv, s.z * inv, s.w * inv};
        ((float4*)(pooled + (size_t)b * 2 * HW_))[q]       = sm4;
        ((float4*)(pooled + (size_t)b * 2 * HW_ + HW_))[q] = m;
    }
}

// ---------------- Kernel 4: 7x7 conv (pad 3) over pooled -> sigmoid -> sa ----------------
__global__ void k_conv_sa(const float* __restrict__ pooled, const float* __restrict__ wsp,
                          float* __restrict__ sa) {
    __shared__ float wv[2 * K_ * K_];
    if (threadIdx.x < 2 * K_ * K_) wv[threadIdx.x] = wsp[threadIdx.x];
    __syncthreads();
    const int idx = blockIdx.x * blockDim.x + threadIdx.x;   // over B*HW
    if (idx >= B_ * HW_) return;
    const int b = idx / HW_;
    const int hw = idx % HW_;
    const int h = hw / W_, w = hw % W_;
    const float* pa = pooled + (size_t)b * 2 * HW_;
    const float* pm = pa + HW_;
    float acc = 0.0f;
    #pragma unroll
    for (int ky = 0; ky < K_; ++ky) {
        const int y = h + ky - 3;
        if (y < 0 || y >= H_) continue;
        #pragma unroll
        for (int kx = 0; kx < K_; ++kx) {
            const int xx = w + kx - 3;
            if (xx < 0 || xx >= W_) continue;
            const int o = y * W_ + xx;
            acc += wv[ky * K_ + kx] * pa[o] + wv[K_ * K_ + ky * K_ + kx] * pm[o];
        }
    }
    sa[idx] = sigmoidf_(acc);
}

// ---------------- Kernel 5: out = x * (1 + ca*sa) ----------------
__global__ void k_finalize(const float* __restrict__ x, const float* __restrict__ ca,
                           const float* __restrict__ sa, float* __restrict__ out) {
    const size_t idx = (size_t)blockIdx.x * blockDim.x + threadIdx.x;  // over B*C*HW/4
    if (idx >= (size_t)B_ * C_ * Q_) return;
    const size_t e = idx * 4;
    const int b  = (int)(e / ((size_t)C_ * HW_));
    const int c  = (int)((e / HW_) % C_);
    const int hw = (int)(e % HW_);
    const float a = ca[b * C_ + c];
    const float4 s4 = *(const float4*)(sa + (size_t)b * HW_ + hw);
    const float4 v  = *(const float4*)(x + e);
    float4 o;
    o.x = v.x * (1.0f + a * s4.x);
    o.y = v.y * (1.0f + a * s4.y);
    o.z = v.z * (1.0f + a * s4.z);
    o.w = v.w * (1.0f + a * s4.w);
    *(float4*)((float*)out + e) = o;
}

extern "C" void kernel_launch(void* const* d_in, const int* in_sizes, int n_in,
                              void* d_out, int out_size, void* d_ws, size_t ws_size,
                              hipStream_t stream) {
    const float* x   = (const float*)d_in[0];
    const float* w1  = (const float*)d_in[1];
    const float* w2  = (const float*)d_in[2];
    const float* wsp = (const float*)d_in[3];
    float* out = (float*)d_out;

    // workspace layout (floats)
    float* ws     = (float*)d_ws;
    float* avg    = ws;                             // B*C
    float* mx     = avg + B_ * C_;                  // B*C
    float* ca     = mx + B_ * C_;                   // B*C
    float* pooled = ca + B_ * C_;                   // B*2*HW
    float* sa     = pooled + (size_t)B_ * 2 * HW_;  // B*HW

    // 1) channel-wise pooling
    k_pool_bc<<<B_ * C_, 256, 0, stream>>>(x, avg, mx);
    // 2) MLP -> channel attention
    k_mlp_ca<<<B_, C_, 0, stream>>>(avg, mx, w1, w2, ca);
    // 3) spatial pooling of x*ca  (grid 49 x 32)
    {
        dim3 g(Q_ / 16, B_);
        k_spatial_pool<<<g, 256, 0, stream>>>(x, ca, pooled);
    }
    // 4) 7x7 conv + sigmoid
    {
        const int n = B_ * HW_;
        k_conv_sa<<<(n + 255) / 256, 256, 0, stream>>>(pooled, wsp, sa);
    }
    // 5) residual finalize
    {
        const size_t n = (size_t)B_ * C_ * Q_;
        k_finalize<<<(int)((n + 255) / 256), 256, 0, stream>>>(x, ca, sa, out);
    }
}